// Round 8
// baseline (161.028 us; speedup 1.0000x reference)
//
#include <hip/hip_runtime.h>
#include <hip/hip_bf16.h>

#define BATCH 16
#define SEQ   2048
#define DIM   128
#define QBLK  64       // q rows per block (4 waves x 16)
#define KVB   32       // kv per tile (split path)
#define NTK   32       // tiles per half (1024/32)
#define L2E   1.4426950408889634f
#define THR   8.0f
#define MSENT -100

typedef __attribute__((ext_vector_type(8))) short bf16x8;
typedef __attribute__((ext_vector_type(4))) float f32x4;
typedef __attribute__((ext_vector_type(4))) int   i32x4;
typedef __attribute__((ext_vector_type(4))) unsigned u32x4;

__device__ __forceinline__ unsigned short f2bf(float f) {
  union { float f; unsigned u; } v; v.f = f;
  return (unsigned short)((v.u + 0x7FFFu + ((v.u >> 16) & 1u)) >> 16);  // RTNE
}
__device__ __forceinline__ unsigned packbf(float a, float b) {
  return ((unsigned)f2bf(b) << 16) | (unsigned)f2bf(a);
}

// ---------------- Pass 1a: K f32 -> bf16 (same layout) ----------------
__global__ __launch_bounds__(256) void cvt_k(const float* __restrict__ K,
                                             short* __restrict__ Kb) {
  const size_t i = ((size_t)blockIdx.x * 256 + threadIdx.x) * 8;
  f32x4 a = __builtin_nontemporal_load((const f32x4*)(K + i));
  f32x4 b = __builtin_nontemporal_load((const f32x4*)(K + i + 4));
  u32x4 o = { packbf(a[0], a[1]), packbf(a[2], a[3]),
              packbf(b[0], b[1]), packbf(b[2], b[3]) };
  *(u32x4*)(Kb + i) = o;
}

// ---------------- Pass 1b: V f32 [b][s][d] -> bf16 Vt [b][d][s] ----------------
__global__ __launch_bounds__(256) void cvt_vt(const float* __restrict__ V,
                                              short* __restrict__ Vt) {
  __shared__ unsigned t32[64][65];
  const int tid = threadIdx.x;
  const int b  = blockIdx.x >> 5;
  const int s0 = (blockIdx.x & 31) * 64;
  #pragma unroll
  for (int it = 0; it < 8; ++it) {
    const int idx = tid + it * 256;
    const int r = idx >> 5, c4 = idx & 31;
    f32x4 x = __builtin_nontemporal_load(
        (const f32x4*)(V + ((size_t)b * SEQ + s0 + r) * DIM + c4 * 4));
    t32[r][c4 * 2]     = packbf(x[0], x[1]);
    t32[r][c4 * 2 + 1] = packbf(x[2], x[3]);
  }
  __syncthreads();
  const int d = tid >> 1, sh = tid & 1;
  unsigned short outv[32];
  #pragma unroll
  for (int j = 0; j < 32; ++j) {
    const unsigned u = t32[sh * 32 + j][d >> 1];
    outv[j] = (d & 1) ? (unsigned short)(u >> 16) : (unsigned short)(u & 0xffff);
  }
  short* op = Vt + ((size_t)b * DIM + d) * SEQ + s0 + sh * 32;
  #pragma unroll
  for (int q = 0; q < 4; ++q) {
    bf16x8 y;
    #pragma unroll
    for (int j = 0; j < 8; ++j) y[j] = (short)outv[q * 8 + j];
    *(bf16x8*)(op + q * 8) = y;
  }
}

// ---------------- async 16B global->LDS ----------------
__device__ __forceinline__ void gload16(const void* g, void* l) {
  __builtin_amdgcn_global_load_lds(
      (const __attribute__((address_space(1))) unsigned*)g,
      (__attribute__((address_space(3))) unsigned*)l, 16, 0, 0);
}

// ---- split-path staging: K [32 rows x 256B], V [128 rows x 64B],
// ---- M [64 rows x 128B].  LDS dest linear; SOURCE pre-swizzled (rule #21).
__device__ __forceinline__ void stage3(const char* __restrict__ Kb2,
                                       const char* __restrict__ Vtb2,
                                       const char* __restrict__ Mb2,
                                       int k0, int w, int l,
                                       void* kbuf, void* vbuf, void* mbuf) {
  #pragma unroll
  for (int it = 0; it < 2; ++it) {
    const int ch = w * 2 + it;                 // 1KB chunk 0..7
    const int r  = ch * 4 + (l >> 4);          // K row (kv) 0..31
    const int sp = (l & 15) ^ (r & 15);        // content(row,s) = s ^ (row&15)
    gload16(Kb2 + (size_t)(k0 + r) * 256 + sp * 16, (char*)kbuf + ch * 1024);
  }
  #pragma unroll
  for (int it = 0; it < 2; ++it) {
    const int ch = w * 2 + it;
    const int d  = ch * 16 + (l >> 2);         // V row (d) 0..127
    const int sp = (l & 3) ^ ((l >> 3) & 3);   // content(d,s) = s ^ ((d>>1)&3)
    gload16(Vtb2 + (size_t)d * (SEQ * 2) + (size_t)k0 * 2 + sp * 16,
            (char*)vbuf + ch * 1024);
  }
  #pragma unroll
  for (int it = 0; it < 2; ++it) {
    const int ch = w * 2 + it;
    const int r  = ch * 8 + (l >> 3);          // mask q-row 0..63
    const int sp = (l & 7) ^ (l >> 3);         // content(row,s) = s ^ (row&7)
    gload16(Mb2 + (size_t)r * (SEQ * 4) + (size_t)k0 * 4 + sp * 16,
            (char*)mbuf + ch * 1024);
  }
}

// ---------------- Pass 2: kv-split flash attention ----------------
// 1024 blocks: (b, q-tile, kv-half).  4 waves x 16 q.  Swapped QK^T, in-reg P.
__global__ __launch_bounds__(256, 3) void attn_split(
    const short* __restrict__ Kbf, const short* __restrict__ Vt,
    const float* __restrict__ Qg, const int* __restrict__ Mg,
    float* __restrict__ O0, float* __restrict__ O1, float2* __restrict__ ML) {
  __shared__ short lds_k[2][KVB * DIM];    // 2 x 8KB
  __shared__ short lds_v[2][DIM * KVB];    // 2 x 8KB
  __shared__ int   lds_m[2][QBLK * KVB];   // 2 x 8KB  (total 48KB)

  const int tid = threadIdx.x;
  const int w = tid >> 6, l = tid & 63, g = l >> 4, lr = l & 15;

  const int blk = blockIdx.x;
  const int swz = (blk & 7) * 128 + (blk >> 3);   // XCD-chunked (1024%8==0)
  const int b   = swz >> 6;
  const int x   = swz & 63;
  const int h   = x >> 5;                          // kv half 0/1
  const int q0  = (x & 31) * QBLK;
  const int kvbase = h * (SEQ / 2);

  const char* Kb2  = (const char*)(Kbf + (size_t)b * SEQ * DIM);
  const char* Vtb2 = (const char*)(Vt  + (size_t)b * DIM * SEQ);
  const char* Mb2  = (const char*)(Mg + (size_t)b * SEQ * SEQ + (size_t)q0 * SEQ);

  stage3(Kb2, Vtb2, Mb2, kvbase, w, l, lds_k[0], lds_v[0], lds_m[0]);
  __builtin_amdgcn_sched_barrier(0);

  // ---- Q fragments (q = lr within wave; B-operand of swapped QK), pre-scaled
  const float scale = 0.08838834764831845f;  // 1/sqrt(128)
  bf16x8 qa[4];
  {
    const float* qbase = Qg + ((size_t)b * SEQ + (size_t)(q0 + w * 16 + lr)) * DIM + g * 8;
    #pragma unroll
    for (int kk = 0; kk < 4; ++kk) {
      f32x4 x0 = *(const f32x4*)(qbase + kk * 32);
      f32x4 x1 = *(const f32x4*)(qbase + kk * 32 + 4);
      bf16x8 f;
      #pragma unroll
      for (int j = 0; j < 4; ++j) {
        f[j]     = (short)f2bf(x0[j] * scale);
        f[j + 4] = (short)f2bf(x1[j] * scale);
      }
      qa[kk] = f;
    }
  }
  __builtin_amdgcn_sched_barrier(0);

  f32x4 acc[8];
  #pragma unroll
  for (int t = 0; t < 8; ++t) acc[t] = (f32x4){0.f, 0.f, 0.f, 0.f};
  float mrow = -1e30f, lsum = 0.f;

  // bpermute source lanes for P redistribution:
  // word wd of target (g,lr): src lane g_src = 2*(g&1) + (wd>>1), value
  // pk[g>>1][wd&1] of that lane (target-side sub select; see R7 post-mortem).
  const int laneA = ((g & 1) << 5) + lr;        // g_src = 2*(g&1)
  const int laneB = ((g & 1) << 5) + 16 + lr;   // g_src = 2*(g&1)+1

  __syncthreads();   // stage(0) drained
  int cur = 0;

  for (int t = 0; t < NTK; ++t) {
    const int k0 = kvbase + t * KVB;
    if (t + 1 < NTK)
      stage3(Kb2, Vtb2, Mb2, k0 + KVB, w, l,
             lds_k[cur ^ 1], lds_v[cur ^ 1], lds_m[cur ^ 1]);
    __builtin_amdgcn_sched_barrier(0);

    const char* kbuf = (const char*)lds_k[cur];
    const char* vbuf = (const char*)lds_v[cur];
    const char* mbuf = (const char*)lds_m[cur];

    // ---- QK^T swapped: s[sub] rows kv=16sub+4g+i, col q=lr
    f32x4 s[2];
    s[0] = (f32x4){0.f, 0.f, 0.f, 0.f};
    s[1] = (f32x4){0.f, 0.f, 0.f, 0.f};
    #pragma unroll
    for (int kk = 0; kk < 4; ++kk) {
      const int S = (((4 * kk + g) ^ lr) << 4);
      bf16x8 kb0 = *(const bf16x8*)(kbuf + lr * 256 + S);
      bf16x8 kb1 = *(const bf16x8*)(kbuf + (16 + lr) * 256 + S);
      s[0] = __builtin_amdgcn_mfma_f32_16x16x32_bf16(kb0, qa[kk], s[0], 0, 0, 0);
      s[1] = __builtin_amdgcn_mfma_f32_16x16x32_bf16(kb1, qa[kk], s[1], 0, 0, 0);
    }

    // ---- mask from LDS (row = w*16+lr, logical slot 4sub+g, swizzled)
    #pragma unroll
    for (int sub = 0; sub < 2; ++sub) {
      const i32x4 mm = *(const i32x4*)(
          mbuf + (w * 16 + lr) * 128 + (((4 * sub + g) ^ (lr & 7)) << 4));
      #pragma unroll
      for (int i = 0; i < 4; ++i)
        if (mm[i] == MSENT) s[sub][i] = -1e30f;
    }

    // ---- online softmax, lane-local (q=lr), defer-max (T13)
    float tm = s[0][0];
    tm = fmaxf(tm, s[0][1]); tm = fmaxf(tm, s[0][2]); tm = fmaxf(tm, s[0][3]);
    tm = fmaxf(tm, s[1][0]); tm = fmaxf(tm, s[1][1]);
    tm = fmaxf(tm, s[1][2]); tm = fmaxf(tm, s[1][3]);
    tm = fmaxf(tm, __shfl_xor(tm, 16));
    tm = fmaxf(tm, __shfl_xor(tm, 32));
    if (__any(tm > mrow + THR)) {
      const float mnew = fmaxf(mrow, tm);
      const float al = __builtin_amdgcn_exp2f((mrow - mnew) * L2E);
      mrow = mnew; lsum *= al;
      float av[4];
      #pragma unroll
      for (int i = 0; i < 4; ++i) av[i] = __shfl(al, 4 * g + i);
      #pragma unroll
      for (int t8 = 0; t8 < 8; ++t8)
        #pragma unroll
        for (int i = 0; i < 4; ++i) acc[t8][i] *= av[i];
    }

    // ---- P = exp2((s-m)*L2E), pack pairs, in-register redistribute (no LDS)
    unsigned pk[2][2];
    #pragma unroll
    for (int sub = 0; sub < 2; ++sub) {
      const float p0 = __builtin_amdgcn_exp2f((s[sub][0] - mrow) * L2E);
      const float p1 = __builtin_amdgcn_exp2f((s[sub][1] - mrow) * L2E);
      const float p2 = __builtin_amdgcn_exp2f((s[sub][2] - mrow) * L2E);
      const float p3 = __builtin_amdgcn_exp2f((s[sub][3] - mrow) * L2E);
      lsum += (p0 + p1) + (p2 + p3);
      pk[sub][0] = packbf(p0, p1);
      pk[sub][1] = packbf(p2, p3);
    }
    // Both subs travel; TARGET picks sub = g>>1 (fix for R7's source-side bug).
    const unsigned s00 = (unsigned)__shfl((int)pk[0][0], laneA);
    const unsigned s01 = (unsigned)__shfl((int)pk[0][1], laneA);
    const unsigned s02 = (unsigned)__shfl((int)pk[0][0], laneB);
    const unsigned s03 = (unsigned)__shfl((int)pk[0][1], laneB);
    const unsigned s10 = (unsigned)__shfl((int)pk[1][0], laneA);
    const unsigned s11 = (unsigned)__shfl((int)pk[1][1], laneA);
    const unsigned s12 = (unsigned)__shfl((int)pk[1][0], laneB);
    const unsigned s13 = (unsigned)__shfl((int)pk[1][1], laneB);
    const bool hi = (g >= 2);
    union { unsigned u[4]; bf16x8 v; } pa;
    pa.u[0] = hi ? s10 : s00;
    pa.u[1] = hi ? s11 : s01;
    pa.u[2] = hi ? s12 : s02;
    pa.u[3] = hi ? s13 : s03;

    // ---- PV: A = P (in reg), B = V (swizzled LDS rows of 64B)
    const int Sv = ((g ^ ((lr >> 1) & 3)) << 4);
    #pragma unroll
    for (int t8 = 0; t8 < 8; ++t8) {
      bf16x8 vb = *(const bf16x8*)(vbuf + (16 * t8 + lr) * 64 + Sv);
      acc[t8] = __builtin_amdgcn_mfma_f32_16x16x32_bf16(pa.v, vb, acc[t8], 0, 0, 0);
    }

    __syncthreads();   // drains stage(t+1)
    cur ^= 1;
  }

  // ---- epilogue: per-row (m, l) + unnormalized O partial
  lsum += __shfl_xor(lsum, 16);
  lsum += __shfl_xor(lsum, 32);
  if (l < 16)
    ML[(size_t)h * (BATCH * SEQ) + (size_t)b * SEQ + q0 + w * 16 + l] =
        make_float2(mrow, lsum);
  float* op = (h == 0 ? O0 : O1) + ((size_t)b * SEQ + (size_t)(q0 + w * 16)) * DIM;
  #pragma unroll
  for (int t8 = 0; t8 < 8; ++t8)
    #pragma unroll
    for (int i = 0; i < 4; ++i)
      op[(4 * g + i) * DIM + 16 * t8 + lr] = acc[t8][i];
}

// ---------------- Pass 3: merge the two kv-halves ----------------
__global__ __launch_bounds__(256) void merge_halves(
    float* __restrict__ O, const float* __restrict__ O1,
    const float2* __restrict__ ML) {
  const int idx = blockIdx.x * 256 + threadIdx.x;
  const int r = idx >> 5, c = (idx & 31) * 4;
  const float2 ml0 = ML[r];
  const float2 ml1 = ML[(size_t)BATCH * SEQ + r];
  const float M  = fmaxf(ml0.x, ml1.x);
  const float w0 = __builtin_amdgcn_exp2f((ml0.x - M) * L2E);
  const float w1 = __builtin_amdgcn_exp2f((ml1.x - M) * L2E);
  const float inv = 1.f / (w0 * ml0.y + w1 * ml1.y);
  f32x4 o0 = *(const f32x4*)(O  + (size_t)r * DIM + c);
  f32x4 o1 = *(const f32x4*)(O1 + (size_t)r * DIM + c);
  f32x4 res = (o0 * w0 + o1 * w1) * inv;
  *(f32x4*)(O + (size_t)r * DIM + c) = res;
}

// ================= fallback: proven R6 kernel (ws too small) =================
#define KVBLK 64
#define NT    (SEQ / KVBLK)
#define PPAD  72

__device__ __forceinline__ void stage_kv2(const char* __restrict__ Kb2,
                                          const char* __restrict__ Vtb2,
                                          int k0, int w, int l,
                                          void* kbuf, void* vbuf) {
  #pragma unroll
  for (int it = 0; it < 4; ++it) {
    const int ch = w * 4 + it;
    const int r  = ch * 4 + (l >> 4);
    const int sg = (l & 15) ^ (r & 15);
    gload16(Kb2 + (size_t)(k0 + r) * 256 + sg * 16, (char*)kbuf + ch * 1024);
  }
  #pragma unroll
  for (int it = 0; it < 4; ++it) {
    const int ch = w * 4 + it;
    const int d2 = ch * 4 + (l >> 4);
    const int Su = (l & 15) ^ (d2 & 15);
    const int d  = 2 * d2 + (Su >> 3);
    const int m  = Su & 7;
    gload16(Vtb2 + (size_t)d * (SEQ * 2) + k0 * 2 + m * 16,
            (char*)vbuf + ch * 1024);
  }
}

__global__ __launch_bounds__(256, 2) void attn_fwd_fb(
    const short* __restrict__ Kbf, const short* __restrict__ Vt,
    const float* __restrict__ Qg, const int* __restrict__ Mg,
    float* __restrict__ Og) {
  __shared__ short lds_k[2][KVBLK * DIM];
  __shared__ short lds_v[2][DIM * KVBLK];
  __shared__ short lds_p[4][16 * PPAD];
  const int tid = threadIdx.x;
  const int w = tid >> 6, l = tid & 63, g = l >> 4, lr = l & 15;
  const int blk = blockIdx.x;
  const int swz = (blk & 7) * 64 + (blk >> 3);
  const int b   = swz >> 5;
  const int q0  = (swz & 31) * QBLK;
  const float scale = 0.08838834764831845f;
  const char* Kb2  = (const char*)(Kbf + (size_t)b * SEQ * DIM);
  const char* Vtb2 = (const char*)(Vt  + (size_t)b * DIM * SEQ);
  const int*  Mr   = Mg + (size_t)b * SEQ * SEQ + (size_t)(q0 + w * 16 + lr) * SEQ;
  stage_kv2(Kb2, Vtb2, 0, w, l, lds_k[0], lds_v[0]);
  __builtin_amdgcn_sched_barrier(0);
  bf16x8 qa[4];
  {
    const float* qbase = Qg + ((size_t)b * SEQ + (size_t)(q0 + w * 16 + lr)) * DIM + g * 8;
    #pragma unroll
    for (int kk = 0; kk < 4; ++kk) {
      f32x4 x0 = *(const f32x4*)(qbase + kk * 32);
      f32x4 x1 = *(const f32x4*)(qbase + kk * 32 + 4);
      bf16x8 f;
      #pragma unroll
      for (int j = 0; j < 4; ++j) {
        f[j] = (short)f2bf(x0[j] * scale);
        f[j + 4] = (short)f2bf(x1[j] * scale);
      }
      qa[kk] = f;
    }
  }
  __builtin_amdgcn_sched_barrier(0);
  i32x4 mreg[4];
  #pragma unroll
  for (int sub = 0; sub < 4; ++sub)
    mreg[sub] = __builtin_nontemporal_load((const i32x4*)(Mr + 16 * sub + 4 * g));
  f32x4 acc[8];
  #pragma unroll
  for (int t = 0; t < 8; ++t) acc[t] = (f32x4){0.f, 0.f, 0.f, 0.f};
  float mrow = -1e30f, lsum = 0.f;
  asm volatile("s_waitcnt vmcnt(4)" ::: "memory");
  __builtin_amdgcn_s_barrier();
  int cur = 0;
  for (int t = 0; t < NT; ++t) {
    const int k0 = t * KVBLK;
    if (t + 1 < NT)
      stage_kv2(Kb2, Vtb2, k0 + KVBLK, w, l, lds_k[cur ^ 1], lds_v[cur ^ 1]);
    __builtin_amdgcn_sched_barrier(0);
    const char* kbuf = (const char*)lds_k[cur];
    const char* vbuf = (const char*)lds_v[cur];
    f32x4 s[4];
    #pragma unroll
    for (int sub = 0; sub < 4; ++sub) s[sub] = (f32x4){0.f, 0.f, 0.f, 0.f};
    #pragma unroll
    for (int kk = 0; kk < 4; ++kk) {
      #pragma unroll
      for (int sub = 0; sub < 4; ++sub) {
        const int krow = sub * 16 + lr;
        const int cb = (64 * kk + 16 * g) ^ (lr << 4);
        bf16x8 kb = *(const bf16x8*)(kbuf + krow * 256 + cb);
        s[sub] = __builtin_amdgcn_mfma_f32_16x16x32_bf16(kb, qa[kk], s[sub], 0, 0, 0);
      }
    }
    #pragma unroll
    for (int sub = 0; sub < 4; ++sub)
      #pragma unroll
      for (int i = 0; i < 4; ++i)
        if (mreg[sub][i] == MSENT) s[sub][i] = -1e30f;
    if (t + 1 < NT) {
      #pragma unroll
      for (int sub = 0; sub < 4; ++sub)
        mreg[sub] = __builtin_nontemporal_load(
            (const i32x4*)(Mr + k0 + KVBLK + 16 * sub + 4 * g));
    }
    float tm = -1e30f;
    #pragma unroll
    for (int sub = 0; sub < 4; ++sub)
      #pragma unroll
      for (int i = 0; i < 4; ++i) tm = fmaxf(tm, s[sub][i]);
    tm = fmaxf(tm, __shfl_xor(tm, 16));
    tm = fmaxf(tm, __shfl_xor(tm, 32));
    if (__any(tm > mrow + THR)) {
      const float mnew = fmaxf(mrow, tm);
      const float al = __builtin_amdgcn_exp2f((mrow - mnew) * L2E);
      mrow = mnew; lsum *= al;
      float av[4];
      #pragma unroll
      for (int i = 0; i < 4; ++i) av[i] = __shfl(al, 4 * g + i);
      #pragma unroll
      for (int t8 = 0; t8 < 8; ++t8)
        #pragma unroll
        for (int i = 0; i < 4; ++i) acc[t8][i] *= av[i];
    }
    {
      unsigned* prow = (unsigned*)&lds_p[w][lr * PPAD];
      #pragma unroll
      for (int sub = 0; sub < 4; ++sub) {
        const float p0 = __builtin_amdgcn_exp2f((s[sub][0] - mrow) * L2E);
        const float p1 = __builtin_amdgcn_exp2f((s[sub][1] - mrow) * L2E);
        const float p2 = __builtin_amdgcn_exp2f((s[sub][2] - mrow) * L2E);
        const float p3 = __builtin_amdgcn_exp2f((s[sub][3] - mrow) * L2E);
        lsum += (p0 + p1) + (p2 + p3);
        prow[8 * sub + 2 * g]     = packbf(p0, p1);
        prow[8 * sub + 2 * g + 1] = packbf(p2, p3);
      }
    }
    bf16x8 pa[2];
    #pragma unroll
    for (int kk = 0; kk < 2; ++kk)
      pa[kk] = *(const bf16x8*)&lds_p[w][lr * PPAD + kk * 32 + g * 8];
    #pragma unroll
    for (int t8 = 0; t8 < 8; ++t8) {
      const int d2 = 8 * t8 + (lr >> 1);
      #pragma unroll
      for (int kk = 0; kk < 2; ++kk) {
        const int S = ((lr & 1) * 8 + 4 * kk + g) ^ (d2 & 15);
        bf16x8 vb = *(const bf16x8*)(vbuf + d2 * 256 + S * 16);
        acc[t8] = __builtin_amdgcn_mfma_f32_16x16x32_bf16(pa[kk], vb, acc[t8], 0, 0, 0);
      }
    }
    if (t + 1 < NT) {
      asm volatile("s_waitcnt vmcnt(4)" ::: "memory");
      __builtin_amdgcn_s_barrier();
    }
    cur ^= 1;
  }
  lsum += __shfl_xor(lsum, 16);
  lsum += __shfl_xor(lsum, 32);
  const float rden = 1.f / lsum;
  float rdv[4];
  #pragma unroll
  for (int i = 0; i < 4; ++i) rdv[i] = __shfl(rden, 4 * g + i);
  float* ob = Og + ((size_t)b * SEQ + (size_t)(q0 + w * 16)) * DIM;
  #pragma unroll
  for (int t8 = 0; t8 < 8; ++t8)
    #pragma unroll
    for (int i = 0; i < 4; ++i)
      ob[(4 * g + i) * DIM + 16 * t8 + lr] = acc[t8][i] * rdv[i];
}

extern "C" void kernel_launch(void* const* d_in, const int* in_sizes, int n_in,
                              void* d_out, int out_size, void* d_ws, size_t ws_size,
                              hipStream_t stream) {
  (void)in_sizes; (void)n_in; (void)out_size;
  const float* Vg = (const float*)d_in[0];
  const float* Kg = (const float*)d_in[1];
  const float* Qg = (const float*)d_in[2];
  const int*   Mg = (const int*)d_in[3];
  float* Og = (float*)d_out;

  const size_t NE = (size_t)BATCH * SEQ * DIM;           // 4,194,304
  short* Kbf = (short*)d_ws;                             // 8 MB
  short* Vt  = Kbf + NE;                                 // 8 MB
  float* O1  = (float*)(Vt + NE);                        // 16.8 MB
  float2* ML = (float2*)(O1 + NE);                       // 0.5 MB
  const size_t need_split = NE * 2 * sizeof(short) + NE * sizeof(float)
                          + (size_t)2 * BATCH * SEQ * sizeof(float2);
  const size_t need_fb    = NE * 2 * sizeof(short);

  cvt_k<<<dim3(BATCH * SEQ * DIM / (8 * 256)), 256, 0, stream>>>(Kg, Kbf);
  cvt_vt<<<dim3(BATCH * (SEQ / 64)), 256, 0, stream>>>(Vg, Vt);

  if (ws_size >= need_split) {
    attn_split<<<dim3(2 * BATCH * (SEQ / QBLK)), 256, 0, stream>>>(
        Kbf, Vt, Qg, Mg, Og, O1, ML);
    merge_halves<<<dim3(BATCH * SEQ * (DIM / 4) / 256), 256, 0, stream>>>(
        Og, O1, ML);
  } else if (ws_size >= need_fb) {
    attn_fwd_fb<<<dim3(BATCH * (SEQ / QBLK)), 256, 0, stream>>>(
        Kbf, Vt, Qg, Mg, Og);
  }
}

// Round 11
// 108.387 us; speedup vs baseline: 1.4857x; 1.4857x over previous
//
#include <hip/hip_runtime.h>
#include <hip/hip_bf16.h>

#define BATCH 16
#define SEQ   2048
#define DIM   128
#define QBLK  64       // q rows per block (4 waves x 16)
#define KVBLK 64
#define NT    (SEQ / KVBLK)
#define PPAD  72       // lds_p row stride (shorts)
#define L2E   1.4426950408889634f
#define THR   8.0f
#define MSENT -100

typedef __attribute__((ext_vector_type(8))) short bf16x8;
typedef __attribute__((ext_vector_type(4))) float f32x4;
typedef __attribute__((ext_vector_type(4))) int   i32x4;
typedef __attribute__((ext_vector_type(4))) unsigned u32x4;

__device__ __forceinline__ unsigned short f2bf(float f) {
  union { float f; unsigned u; } v; v.f = f;
  return (unsigned short)((v.u + 0x7FFFu + ((v.u >> 16) & 1u)) >> 16);  // RTNE
}
__device__ __forceinline__ unsigned packbf(float a, float b) {
  return ((unsigned)f2bf(b) << 16) | (unsigned)f2bf(a);
}

// ---------------- Pass 1a: K f32 -> bf16 (same layout) ----------------
__global__ __launch_bounds__(256) void cvt_k(const float* __restrict__ K,
                                             short* __restrict__ Kb) {
  const size_t i = ((size_t)blockIdx.x * 256 + threadIdx.x) * 8;
  f32x4 a = __builtin_nontemporal_load((const f32x4*)(K + i));
  f32x4 b = __builtin_nontemporal_load((const f32x4*)(K + i + 4));
  u32x4 o = { packbf(a[0], a[1]), packbf(a[2], a[3]),
              packbf(b[0], b[1]), packbf(b[2], b[3]) };
  *(u32x4*)(Kb + i) = o;
}

// ---------------- Pass 1b: V f32 [b][s][d] -> bf16 Vt [b][d][s] ----------------
__global__ __launch_bounds__(256) void cvt_vt(const float* __restrict__ V,
                                              short* __restrict__ Vt) {
  __shared__ unsigned t32[64][65];
  const int tid = threadIdx.x;
  const int b  = blockIdx.x >> 5;
  const int s0 = (blockIdx.x & 31) * 64;
  #pragma unroll
  for (int it = 0; it < 8; ++it) {
    const int idx = tid + it * 256;
    const int r = idx >> 5, c4 = idx & 31;
    f32x4 x = __builtin_nontemporal_load(
        (const f32x4*)(V + ((size_t)b * SEQ + s0 + r) * DIM + c4 * 4));
    t32[r][c4 * 2]     = packbf(x[0], x[1]);
    t32[r][c4 * 2 + 1] = packbf(x[2], x[3]);
  }
  __syncthreads();
  const int d = tid >> 1, sh = tid & 1;
  unsigned short outv[32];
  #pragma unroll
  for (int j = 0; j < 32; ++j) {
    const unsigned u = t32[sh * 32 + j][d >> 1];
    outv[j] = (d & 1) ? (unsigned short)(u >> 16) : (unsigned short)(u & 0xffff);
  }
  short* op = Vt + ((size_t)b * DIM + d) * SEQ + s0 + sh * 32;
  #pragma unroll
  for (int q = 0; q < 4; ++q) {
    bf16x8 y;
    #pragma unroll
    for (int j = 0; j < 8; ++j) y[j] = (short)outv[q * 8 + j];
    *(bf16x8*)(op + q * 8) = y;
  }
}

// ---------------- async 16B global->LDS ----------------
__device__ __forceinline__ void gload16(const void* g, void* l) {
  __builtin_amdgcn_global_load_lds(
      (const __attribute__((address_space(1))) unsigned*)g,
      (__attribute__((address_space(3))) unsigned*)l, 16, 0, 0);
}

// K tile [64 rows x 256B] into LDS; linear dest, pre-swizzled source (#21).
__device__ __forceinline__ void stage_k(const char* __restrict__ Kb2,
                                        int k0, int w, int l, void* kbuf) {
  #pragma unroll
  for (int it = 0; it < 4; ++it) {
    const int ch = w * 4 + it;
    const int r  = ch * 4 + (l >> 4);
    const int sg = (l & 15) ^ (r & 15);
    gload16(Kb2 + (size_t)(k0 + r) * 256 + sg * 16, (char*)kbuf + ch * 1024);
  }
}
// V tile [64 paired-d rows x 256B] into LDS; same both-sides swizzle scheme.
__device__ __forceinline__ void stage_v(const char* __restrict__ Vtb2,
                                        int k0, int w, int l, void* vbuf) {
  #pragma unroll
  for (int it = 0; it < 4; ++it) {
    const int ch = w * 4 + it;
    const int d2 = ch * 4 + (l >> 4);
    const int Su = (l & 15) ^ (d2 & 15);
    const int d  = 2 * d2 + (Su >> 3);
    const int m  = Su & 7;
    gload16(Vtb2 + (size_t)d * (SEQ * 2) + (size_t)k0 * 2 + m * 16,
            (char*)vbuf + ch * 1024);
  }
}

// One pipelined tile: softmax/P/PV of tile T overlapped with QK of tile T+1.
// Buffer rotation (verified NT=4 walk-through): iter T (parity PAR) stages
// K(T+2)->k[PAR], V(T+1)->v[PAR^1]; QK(T+1) reads k[PAR^1]; PV(T) reads v[PAR].
// ALL sync via __syncthreads() (full vmcnt/lgkmcnt drain + fence) — conservative.
#define TILE_BODY(T, PAR, SA, SB, MA, MB)                                      \
  {                                                                            \
    if ((T) + 2 < NT) stage_k(Kb2, ((T) + 2) * KVBLK, w, l, lds_k[(PAR)]);     \
    if ((T) + 1 < NT) stage_v(Vtb2, ((T) + 1) * KVBLK, w, l, lds_v[(PAR) ^ 1]);\
    __builtin_amdgcn_sched_barrier(0);                                         \
    /* mask apply + online softmax (tile T), lane-local q = lr */              \
    _Pragma("unroll") for (int sub = 0; sub < 4; ++sub)                        \
        _Pragma("unroll") for (int i = 0; i < 4; ++i)                          \
            if (MA[sub][i] == MSENT) SA[sub][i] = -1e30f;                      \
    {                                                                          \
      float tm = -1e30f;                                                       \
      _Pragma("unroll") for (int sub = 0; sub < 4; ++sub)                      \
          _Pragma("unroll") for (int i = 0; i < 4; ++i)                        \
              tm = fmaxf(tm, SA[sub][i]);                                      \
      tm = fmaxf(tm, __shfl_xor(tm, 16));                                      \
      tm = fmaxf(tm, __shfl_xor(tm, 32));                                      \
      if (__any(tm > mrow + THR)) {                                            \
        const float mnew = fmaxf(mrow, tm);                                    \
        const float al = __builtin_amdgcn_exp2f((mrow - mnew) * L2E);          \
        mrow = mnew; lsum *= al;                                               \
        float av[4];                                                           \
        _Pragma("unroll") for (int i = 0; i < 4; ++i)                          \
            av[i] = __shfl(al, 4 * g + i);                                     \
        _Pragma("unroll") for (int t8 = 0; t8 < 8; ++t8)                       \
            _Pragma("unroll") for (int i = 0; i < 4; ++i)                      \
                acc[t8][i] *= av[i];                                           \
      }                                                                        \
    }                                                                          \
    /* mask(T+1) prefetch (register, drained at the tile-end barrier) */       \
    if ((T) + 1 < NT) {                                                        \
      _Pragma("unroll") for (int sub = 0; sub < 4; ++sub)                      \
          MB[sub] = __builtin_nontemporal_load(                                \
              (const i32x4*)(Mr + ((T) + 1) * KVBLK + 16 * sub + 4 * g));      \
    }                                                                          \
    /* QK(T+1) from k[(PAR)^1] — MFMA pipe; overlaps P VALU below */           \
    if ((T) + 1 < NT) {                                                        \
      const char* kb_ = (const char*)lds_k[(PAR) ^ 1];                         \
      _Pragma("unroll") for (int sub = 0; sub < 4; ++sub)                      \
          SB[sub] = (f32x4){0.f, 0.f, 0.f, 0.f};                               \
      __builtin_amdgcn_s_setprio(1);                                           \
      _Pragma("unroll") for (int kk = 0; kk < 4; ++kk) {                       \
        const int cb = (64 * kk + 16 * g) ^ (lr << 4);                         \
        _Pragma("unroll") for (int sub = 0; sub < 4; ++sub) {                  \
          bf16x8 kb = *(const bf16x8*)(kb_ + (sub * 16 + lr) * 256 + cb);      \
          SB[sub] = __builtin_amdgcn_mfma_f32_16x16x32_bf16(kb, qa[kk],        \
                                                            SB[sub], 0, 0, 0); \
        }                                                                      \
      }                                                                        \
      __builtin_amdgcn_s_setprio(0);                                           \
    }                                                                          \
    /* P(T) = exp2 + packbf, LDS roundtrip, PV(T) */                           \
    {                                                                          \
      unsigned* prow = (unsigned*)&lds_p[w][lr * PPAD];                        \
      _Pragma("unroll") for (int sub = 0; sub < 4; ++sub) {                    \
        const float p0 = __builtin_amdgcn_exp2f((SA[sub][0] - mrow) * L2E);    \
        const float p1 = __builtin_amdgcn_exp2f((SA[sub][1] - mrow) * L2E);    \
        const float p2 = __builtin_amdgcn_exp2f((SA[sub][2] - mrow) * L2E);    \
        const float p3 = __builtin_amdgcn_exp2f((SA[sub][3] - mrow) * L2E);    \
        lsum += (p0 + p1) + (p2 + p3);                                         \
        prow[8 * sub + 2 * g]     = packbf(p0, p1);                            \
        prow[8 * sub + 2 * g + 1] = packbf(p2, p3);                            \
      }                                                                        \
      bf16x8 pa0 = *(const bf16x8*)&lds_p[w][lr * PPAD + g * 8];               \
      bf16x8 pa1 = *(const bf16x8*)&lds_p[w][lr * PPAD + 32 + g * 8];          \
      const char* vb_ = (const char*)lds_v[(PAR)];                             \
      __builtin_amdgcn_s_setprio(1);                                           \
      _Pragma("unroll") for (int t8 = 0; t8 < 8; ++t8) {                       \
        const int d2 = 8 * t8 + (lr >> 1);                                     \
        const int S0 = (((lr & 1) * 8 + 0 + g) ^ (d2 & 15)) * 16;              \
        const int S1 = (((lr & 1) * 8 + 4 + g) ^ (d2 & 15)) * 16;              \
        bf16x8 v0 = *(const bf16x8*)(vb_ + d2 * 256 + S0);                     \
        acc[t8] = __builtin_amdgcn_mfma_f32_16x16x32_bf16(pa0, v0, acc[t8],    \
                                                          0, 0, 0);            \
        bf16x8 v1 = *(const bf16x8*)(vb_ + d2 * 256 + S1);                     \
        acc[t8] = __builtin_amdgcn_mfma_f32_16x16x32_bf16(pa1, v1, acc[t8],    \
                                                          0, 0, 0);            \
      }                                                                        \
      __builtin_amdgcn_s_setprio(0);                                           \
    }                                                                          \
    if ((T) + 1 < NT) __syncthreads();                                         \
  }

// ---------------- Pass 2: pipelined flash attention (swapped QK^T) -----------
__global__ __launch_bounds__(256, 2) void attn_fwd(
    const short* __restrict__ Kbf, const short* __restrict__ Vt,
    const float* __restrict__ Qg, const int* __restrict__ Mg,
    float* __restrict__ Og) {
  __shared__ short lds_k[2][KVBLK * DIM];   // 2 x 16KB
  __shared__ short lds_v[2][DIM * KVBLK];   // 2 x 16KB
  __shared__ short lds_p[4][16 * PPAD];     // 9KB

  const int tid = threadIdx.x;
  const int w = tid >> 6, l = tid & 63, g = l >> 4, lr = l & 15;

  const int blk = blockIdx.x;
  const int swz = (blk & 7) * 64 + (blk >> 3);   // XCD-chunked (512 % 8 == 0)
  const int b   = swz >> 5;
  const int q0  = (swz & 31) * QBLK;

  const float scale = 0.08838834764831845f;  // 1/sqrt(128)

  const char* Kb2  = (const char*)(Kbf + (size_t)b * SEQ * DIM);
  const char* Vtb2 = (const char*)(Vt  + (size_t)b * DIM * SEQ);
  const int*  Mr   = Mg + (size_t)b * SEQ * SEQ + (size_t)(q0 + w * 16 + lr) * SEQ;

  // ---- stage K(0), K(1), V(0); prefetch mask(0)
  stage_k(Kb2, 0,     w, l, lds_k[0]);
  stage_k(Kb2, KVBLK, w, l, lds_k[1]);
  stage_v(Vtb2, 0,    w, l, lds_v[0]);
  __builtin_amdgcn_sched_barrier(0);
  i32x4 mA[4], mB[4];
  #pragma unroll
  for (int sub = 0; sub < 4; ++sub)
    mA[sub] = __builtin_nontemporal_load((const i32x4*)(Mr + 16 * sub + 4 * g));

  // ---- Q fragments (q = lr; B operand of swapped QK), pre-scaled
  bf16x8 qa[4];
  {
    const float* qbase = Qg + ((size_t)b * SEQ + (size_t)(q0 + w * 16 + lr)) * DIM + g * 8;
    #pragma unroll
    for (int kk = 0; kk < 4; ++kk) {
      f32x4 x0 = *(const f32x4*)(qbase + kk * 32);
      f32x4 x1 = *(const f32x4*)(qbase + kk * 32 + 4);
      bf16x8 f;
      #pragma unroll
      for (int j = 0; j < 4; ++j) {
        f[j]     = (short)f2bf(x0[j] * scale);
        f[j + 4] = (short)f2bf(x1[j] * scale);
      }
      qa[kk] = f;
    }
  }

  f32x4 acc[8];
  #pragma unroll
  for (int t = 0; t < 8; ++t) acc[t] = (f32x4){0.f, 0.f, 0.f, 0.f};
  float mrow = -1e30f, lsum = 0.f;

  __syncthreads();   // full drain: K(0),K(1),V(0),mask(0),Q all landed

  // ---- prologue QK(0) -> sA
  f32x4 sA[4], sB[4];
  #pragma unroll
  for (int sub = 0; sub < 4; ++sub) sA[sub] = (f32x4){0.f, 0.f, 0.f, 0.f};
  {
    const char* kb_ = (const char*)lds_k[0];
    #pragma unroll
    for (int kk = 0; kk < 4; ++kk) {
      const int cb = (64 * kk + 16 * g) ^ (lr << 4);
      #pragma unroll
      for (int sub = 0; sub < 4; ++sub) {
        bf16x8 kb = *(const bf16x8*)(kb_ + (sub * 16 + lr) * 256 + cb);
        sA[sub] = __builtin_amdgcn_mfma_f32_16x16x32_bf16(kb, qa[kk], sA[sub], 0, 0, 0);
      }
    }
  }
  __syncthreads();   // all waves done reading k[0] before iter 0 overwrites it

  for (int t = 0; t < NT; t += 2) {
    TILE_BODY(t,     0, sA, sB, mA, mB);
    TILE_BODY(t + 1, 1, sB, sA, mB, mA);
  }

  // ---- finalize: full row sum, normalize, store
  lsum += __shfl_xor(lsum, 16);
  lsum += __shfl_xor(lsum, 32);
  const float rden = 1.f / lsum;   // valid for q = lr
  float rdv[4];
  #pragma unroll
  for (int i = 0; i < 4; ++i) rdv[i] = __shfl(rden, 4 * g + i);
  float* ob = Og + ((size_t)b * SEQ + (size_t)(q0 + w * 16)) * DIM;
  #pragma unroll
  for (int t8 = 0; t8 < 8; ++t8)
    #pragma unroll
    for (int i = 0; i < 4; ++i)
      ob[(4 * g + i) * DIM + 16 * t8 + lr] = acc[t8][i] * rdv[i];
}

extern "C" void kernel_launch(void* const* d_in, const int* in_sizes, int n_in,
                              void* d_out, int out_size, void* d_ws, size_t ws_size,
                              hipStream_t stream) {
  (void)in_sizes; (void)n_in; (void)out_size; (void)ws_size;
  const float* Vg = (const float*)d_in[0];
  const float* Kg = (const float*)d_in[1];
  const float* Qg = (const float*)d_in[2];
  const int*   Mg = (const int*)d_in[3];
  float* Og = (float*)d_out;

  short* Kbf = (short*)d_ws;                       // 8 MB
  short* Vt  = Kbf + (size_t)BATCH * SEQ * DIM;    // 8 MB
  cvt_k<<<dim3(BATCH * SEQ * DIM / (8 * 256)), 256, 0, stream>>>(Kg, Kbf);
  cvt_vt<<<dim3(BATCH * (SEQ / 64)), 256, 0, stream>>>(Vg, Vt);
  attn_fwd<<<dim3(BATCH * (SEQ / QBLK)), 256, 0, stream>>>(Kbf, Vt, Qg, Mg, Og);
}